// Round 9
// baseline (120.192 us; speedup 1.0000x reference)
//
#include <hip/hip_runtime.h>
#include <hip/hip_bf16.h>

// AdaptiveGraphNetwork via MFMA 16x16x32 bf16. B=4096, N=64, D=32, H=64.
//
// v8: ZERO-BARRIER independent-wave structure. v1-v7 all shared 2-4 block-wide
// sync points per batch (4-wave lockstep) and all landed 31-34us kernel
// regardless of instruction count / occupancy / latency trims. v8 removes the
// coupling: edges are owned by DST node; wave w owns 32 nodes (half batch,
// 4 waves = 2 batches/iter) and computes both incoming edge messages itself:
//   h_fwd(n) = relu(x[n]@W1a + x[n+1]@W1b + bm1)   (valid n<=62)
//   h_bwd(n) = relu(x[n]@W1a + x[n-1]@W1b + bm1)   (valid n>=1)
// "Gather" = +-1-shifted contiguous global loads (no sX staging, no barrier).
// "Scatter" = in-register masked add: fwd/bwd msg C-frags share dst-node
// columns: m[n] = [n!=63]*relu(cf+bm2) + [n!=0]*relu(cb+bm2).
// All LDS regions (sH/sM rows) are per-wave-owned -> phase boundaries are
// wave-local lgkmcnt fences; the only s_barriers are 2 in the prologue
// (weight-frag LDS staging -> reg hoist -> frag region aliased under sH).
// LDS = sH 36.9K + sM 10.2K + bias 0.8K = 47.9KB -> 3 blocks/CU (no LB clamp:
// v3/v5 lesson). Weights in regs (B1 32 + W2/W3/W4 64 VGPR), biases in LDS.
//
// Fragment maps (m89/m91-verified): A[m=lane&15][k=quad*8+j],
// B[k=quad*8+j][n=lane&15], C/D[row=quad*4+reg][col=lane&15].
// A-frag of W^T == B-frag of W: one fragment image serves both orientations.

typedef __bf16 bf16x8 __attribute__((ext_vector_type(8)));
typedef float  f32x4  __attribute__((ext_vector_type(4)));
typedef unsigned short u16;

#define NBATCH 8              // batches per WG; 2 per iteration (1/2 per wave)
#define ITERS (NBATCH / 2)
#define HS 72                 // sH row stride in u16 (144 B, 16B-aligned)
#define MS 40                 // sM row stride in u16 (80 B, 16B-aligned)

// Prologue-only frag staging (aliased under sH, dead after reg hoist):
#define FB2_OFF 0                       // 4 frags * 512 u16
#define FB3_OFF (FB2_OFF + 4 * 512)     // 8 frags
#define FB4_OFF (FB3_OFF + 8 * 512)     // 4 frags (ends 8192 < 18432)
// Persistent regions:
#define SH_OFF   0                      // 256 rows * 72 u16 = 18432
#define SM_OFF   (SH_OFF + 256 * HS)    // 18432 : 128 rows * 40 u16
#define BIAS_OFF (SM_OFF + 128 * MS)    // 23552 : 192 f32 = 384 u16
#define SMEM_U16 (BIAS_OFF + 384)       // 23936 u16 = 47872 B -> 3 blocks/CU

__device__ __forceinline__ u16 f2b(float f) { return __builtin_bit_cast(u16, (__bf16)f); }
__device__ __forceinline__ f32x4 MFMA(bf16x8 a, bf16x8 b, f32x4 c) {
    return __builtin_amdgcn_mfma_f32_16x16x32_bf16(a, b, c, 0, 0, 0);
}
__device__ __forceinline__ bf16x8 pack8(float4 a, float4 b) {
    bf16x8 r = {(__bf16)a.x, (__bf16)a.y, (__bf16)a.z, (__bf16)a.w,
                (__bf16)b.x, (__bf16)b.y, (__bf16)b.z, (__bf16)b.w};
    return r;
}
__device__ __forceinline__ uint2 relu_pack4(f32x4 acc, f32x4 bias) {
    uint2 o;
    o.x = (unsigned)f2b(fmaxf(acc[0] + bias[0], 0.f)) |
          ((unsigned)f2b(fmaxf(acc[1] + bias[1], 0.f)) << 16);
    o.y = (unsigned)f2b(fmaxf(acc[2] + bias[2], 0.f)) |
          ((unsigned)f2b(fmaxf(acc[3] + bias[3], 0.f)) << 16);
    return o;
}
// Wave-local LDS producer->consumer fence (same-wave ds ops are in-order).
__device__ __forceinline__ void wave_lds_fence() {
    asm volatile("s_waitcnt lgkmcnt(0)" ::: "memory");
}
// Cross-wave barrier draining LDS only (prologue use).
__device__ __forceinline__ void barrier_lds() {
    asm volatile("s_waitcnt lgkmcnt(0)" ::: "memory");
    __builtin_amdgcn_s_barrier();
    asm volatile("" ::: "memory");
}

__global__ __launch_bounds__(256, 2)
void agn_mfma(const float* __restrict__ x, const float* __restrict__ Wm1,
              const float* __restrict__ bm1, const float* __restrict__ Wm2,
              const float* __restrict__ bm2, const float* __restrict__ Wu1,
              const float* __restrict__ bu1, const float* __restrict__ Wu2,
              const float* __restrict__ bu2, const float* __restrict__ rw_p,
              float* __restrict__ out)
{
    __shared__ __align__(16) u16 smem[SMEM_U16];  // 47872 B

    const int t = threadIdx.x;
    const int w = t >> 6;
    const int lane = t & 63;
    const int ln = lane & 15;
    const int q  = lane >> 4;
    const int bl = w >> 1;          // which batch of the iteration pair
    const int g0 = (w & 1) * 32;    // node-half base within the batch

    float* biasL = (float*)&smem[BIAS_OFF];  // [0..63]=bm1, [64..127]=bu1,
                                             // [128..159]=bm2, [160..191]=bu2

    // ---------- prologue: biases (persistent) + frag images (transient) ----
    if (t < 64)  { biasL[t] = bm1[t]; biasL[64 + t] = bu1[t]; }
    if (t < 32)  { biasL[128 + t] = bm2[t]; biasL[160 + t] = bu2[t]; }
    if (w == 0) {                       // B2 frags: f = ks*2 + s
#pragma unroll
        for (int ks = 0; ks < 2; ++ks)
#pragma unroll
            for (int s = 0; s < 2; ++s) {
                bf16x8 v;
#pragma unroll
                for (int j = 0; j < 8; ++j)
                    v[j] = (__bf16)Wm2[(ks * 32 + q * 8 + j) * 32 + s * 16 + ln];
                *(uint4*)&smem[FB2_OFF + (ks * 2 + s) * 512 + lane * 8] =
                    __builtin_bit_cast(uint4, v);
            }
    } else if (w == 1 || w == 2) {      // B3 frags: f = ks*4 + ht, ks = w-1
        const int ks = w - 1;
#pragma unroll
        for (int ht = 0; ht < 4; ++ht) {
            bf16x8 v;
#pragma unroll
            for (int j = 0; j < 8; ++j)
                v[j] = (__bf16)Wu1[(ks * 32 + q * 8 + j) * 64 + ht * 16 + ln];
            *(uint4*)&smem[FB3_OFF + (ks * 4 + ht) * 512 + lane * 8] =
                __builtin_bit_cast(uint4, v);
        }
    } else {                            // B4 frags: f = ks*2 + s
#pragma unroll
        for (int ks = 0; ks < 2; ++ks)
#pragma unroll
            for (int s = 0; s < 2; ++s) {
                bf16x8 v;
#pragma unroll
                for (int j = 0; j < 8; ++j)
                    v[j] = (__bf16)Wu2[(ks * 32 + q * 8 + j) * 32 + s * 16 + ln];
                *(uint4*)&smem[FB4_OFF + (ks * 2 + s) * 512 + lane * 8] =
                    __builtin_bit_cast(uint4, v);
            }
    }

    // Hot B1 fragments straight from global.
    bf16x8 B1a[4], B1b[4];
#pragma unroll
    for (int nt = 0; nt < 4; ++nt)
#pragma unroll
        for (int j = 0; j < 8; ++j) {
            B1a[nt][j] = (__bf16)Wm1[(q * 8 + j) * 64 + nt * 16 + ln];
            B1b[nt][j] = (__bf16)Wm1[(32 + q * 8 + j) * 64 + nt * 16 + ln];
        }

    barrier_lds();  // frag images complete

    // Hoist W2/W3/W4 fragment images into registers (~64 VGPR).
    bf16x8 W2[2][2], W3[2][4], W4[2][2];
#pragma unroll
    for (int ks = 0; ks < 2; ++ks) {
#pragma unroll
        for (int s = 0; s < 2; ++s) {
            W2[ks][s] = __builtin_bit_cast(bf16x8, *(const uint4*)&smem[FB2_OFF + (ks * 2 + s) * 512 + lane * 8]);
            W4[ks][s] = __builtin_bit_cast(bf16x8, *(const uint4*)&smem[FB4_OFF + (ks * 2 + s) * 512 + lane * 8]);
        }
#pragma unroll
        for (int ht = 0; ht < 4; ++ht)
            W3[ks][ht] = __builtin_bit_cast(bf16x8, *(const uint4*)&smem[FB3_OFF + (ks * 4 + ht) * 512 + lane * 8]);
    }
    barrier_lds();  // frag region dead; sH may alias it.  LAST barrier.

    const float rw = rw_p[0];
    const float om = 1.f - rw;
    const size_t base = (size_t)blockIdx.x * (NBATCH * 64 * 32);

    for (int it = 0; it < ITERS; ++it) {
        const float* xb = x + base + (size_t)(it * 2 + bl) * (64 * 32);
        float*       ob = out + base + (size_t)(it * 2 + bl) * (64 * 32);

        bf16x8 Xd[2];  // dst-node x frags, reused in phase C

        // ===== Phase A: h_fwd / h_bwd for this wave's 32 nodes =====
#pragma unroll
        for (int nt = 0; nt < 2; ++nt) {
            const int n = g0 + nt * 16 + ln;              // in-batch node
            const float* pd = xb + n * 32 + q * 8;
            float4 d0 = *(const float4*)pd, d1 = *(const float4*)(pd + 4);
            Xd[nt] = pack8(d0, d1);
            const int nn = (n == 63) ? n : n + 1;         // clamp; masked later
            const int np = (n == 0)  ? n : n - 1;
            const float* pn = xb + nn * 32 + q * 8;
            const float* pp = xb + np * 32 + q * 8;
            float4 a0 = *(const float4*)pn, a1 = *(const float4*)(pn + 4);
            float4 b0 = *(const float4*)pp, b1 = *(const float4*)(pp + 4);
            bf16x8 Xn = pack8(a0, a1);
            bf16x8 Xp = pack8(b0, b1);
            u16* rf = &smem[SH_OFF + (w * 64 + nt * 16 + ln) * HS];        // fwd h row
            u16* rb = &smem[SH_OFF + (w * 64 + 32 + nt * 16 + ln) * HS];   // bwd h row
#pragma unroll
            for (int ht = 0; ht < 4; ++ht) {
                f32x4 bias = *(const f32x4*)&biasL[ht * 16 + q * 4];
                f32x4 af = {0.f, 0.f, 0.f, 0.f};
                af = MFMA(B1a[ht], Xd[nt], af);
                af = MFMA(B1b[ht], Xn, af);
                *(uint2*)&rf[ht * 16 + q * 4] = relu_pack4(af, bias);
                f32x4 ab = {0.f, 0.f, 0.f, 0.f};
                ab = MFMA(B1a[ht], Xd[nt], ab);
                ab = MFMA(B1b[ht], Xp, ab);
                *(uint2*)&rb[ht * 16 + q * 4] = relu_pack4(ab, bias);
            }
        }
        wave_lds_fence();

        // ===== Phase B: msgs + in-register masked scatter -> sM =====
#pragma unroll
        for (int nt = 0; nt < 2; ++nt) {
            const int n = g0 + nt * 16 + ln;   // this lane's output column node
            const u16* rf = &smem[SH_OFF + (w * 64 + nt * 16 + ln) * HS];
            const u16* rb = &smem[SH_OFF + (w * 64 + 32 + nt * 16 + ln) * HS];
            bf16x8 hf0 = __builtin_bit_cast(bf16x8, *(const uint4*)&rf[q * 8]);
            bf16x8 hf1 = __builtin_bit_cast(bf16x8, *(const uint4*)&rf[32 + q * 8]);
            bf16x8 hb0 = __builtin_bit_cast(bf16x8, *(const uint4*)&rb[q * 8]);
            bf16x8 hb1 = __builtin_bit_cast(bf16x8, *(const uint4*)&rb[32 + q * 8]);
#pragma unroll
            for (int s = 0; s < 2; ++s) {
                f32x4 bias = *(const f32x4*)&biasL[128 + s * 16 + q * 4];
                f32x4 cf = {0.f, 0.f, 0.f, 0.f};
                f32x4 cb = {0.f, 0.f, 0.f, 0.f};
                cf = MFMA(W2[0][s], hf0, cf); cf = MFMA(W2[1][s], hf1, cf);
                cb = MFMA(W2[0][s], hb0, cb); cb = MFMA(W2[1][s], hb1, cb);
                float m4[4];
#pragma unroll
                for (int r = 0; r < 4; ++r) {
                    float vf = (n != 63) ? fmaxf(cf[r] + bias[r], 0.f) : 0.f;
                    float vb = (n != 0)  ? fmaxf(cb[r] + bias[r], 0.f) : 0.f;
                    m4[r] = vf + vb;
                }
                uint2 o;
                o.x = (unsigned)f2b(m4[0]) | ((unsigned)f2b(m4[1]) << 16);
                o.y = (unsigned)f2b(m4[2]) | ((unsigned)f2b(m4[3]) << 16);
                *(uint2*)&smem[SM_OFF + (bl * 64 + n) * MS + s * 16 + q * 4] = o;
            }
        }
        wave_lds_fence();

        // ===== Phase C: hu^T = Wu1^T @ [x | m]^T, relu -> sH (alias fwd rows) =====
#pragma unroll
        for (int nt = 0; nt < 2; ++nt) {
            const int n = g0 + nt * 16 + ln;
            bf16x8 A1 = __builtin_bit_cast(bf16x8, *(const uint4*)&smem[SM_OFF + (bl * 64 + n) * MS + q * 8]);
            u16* rh = &smem[SH_OFF + (w * 64 + nt * 16 + ln) * HS];
#pragma unroll
            for (int ht = 0; ht < 4; ++ht) {
                f32x4 bias = *(const f32x4*)&biasL[64 + ht * 16 + q * 4];
                f32x4 acc = {0.f, 0.f, 0.f, 0.f};
                acc = MFMA(W3[0][ht], Xd[nt], acc);
                acc = MFMA(W3[1][ht], A1, acc);
                *(uint2*)&rh[ht * 16 + q * 4] = relu_pack4(acc, bias);
            }
        }
        wave_lds_fence();

        // ===== Phase D: out^T = Wu2^T @ hu^T; residual; full-line stores =====
#pragma unroll
        for (int nt = 0; nt < 2; ++nt) {
            const int n = g0 + nt * 16 + ln;
            const u16* rh = &smem[SH_OFF + (w * 64 + nt * 16 + ln) * HS];
            bf16x8 A0 = __builtin_bit_cast(bf16x8, *(const uint4*)&rh[q * 8]);
            bf16x8 A1 = __builtin_bit_cast(bf16x8, *(const uint4*)&rh[32 + q * 8]);
#pragma unroll
            for (int s = 0; s < 2; ++s) {
                f32x4 bias = *(const f32x4*)&biasL[160 + s * 16 + q * 4];
                f32x4 acc = {0.f, 0.f, 0.f, 0.f};
                acc = MFMA(W4[0][s], A0, acc);
                acc = MFMA(W4[1][s], A1, acc);
                float4 xv = *(const float4*)(xb + n * 32 + s * 16 + q * 4);
                float4 o;
                o.x = rw * (acc[0] + bias[0]) + om * xv.x;
                o.y = rw * (acc[1] + bias[1]) + om * xv.y;
                o.z = rw * (acc[2] + bias[2]) + om * xv.z;
                o.w = rw * (acc[3] + bias[3]) + om * xv.w;
                *(float4*)(ob + n * 32 + s * 16 + q * 4) = o;
            }
        }
        wave_lds_fence();  // drain before next iter overwrites this wave's rows
    }
}

extern "C" void kernel_launch(void* const* d_in, const int* in_sizes, int n_in,
                              void* d_out, int out_size, void* d_ws, size_t ws_size,
                              hipStream_t stream) {
    const float* x   = (const float*)d_in[0];
    const float* Wm1 = (const float*)d_in[1];
    const float* bm1 = (const float*)d_in[2];
    const float* Wm2 = (const float*)d_in[3];
    const float* bm2 = (const float*)d_in[4];
    const float* Wu1 = (const float*)d_in[5];
    const float* bu1 = (const float*)d_in[6];
    const float* Wu2 = (const float*)d_in[7];
    const float* bu2 = (const float*)d_in[8];
    const float* rw  = (const float*)d_in[9];
    float* out = (float*)d_out;

    const int B = in_sizes[0] / (64 * 32);
    agn_mfma<<<B / NBATCH, 256, 0, stream>>>(x, Wm1, bm1, Wm2, bm2, Wu1, bu1, Wu2, bu2, rw, out);
}